// Round 1
// baseline (478.075 us; speedup 1.0000x reference)
//
#include <hip/hip_runtime.h>
#include <math.h>

#define BATCH 64
#define IC 2048
// J = M = N = 16
#define NI 16            // i's per block (serial)
#define NB 16            // b's per block
#define NG (IC / NI)     // 128 i-groups
#define NBG (BATCH / NB) // 4 b-groups

// thread mapping: tid = m*16 + j  (j = tid&15 -> intra-wave softmax over j)
template <bool FIRST>
__global__ __launch_bounds__(256, 2) void pass_kernel(
    const float* __restrict__ Wt,      // [IC, 16, 16, 16]  (i, j, n, m)
    const float* __restrict__ inp,     // [BATCH, IC, 16]
    const float* __restrict__ vcum,    // [BATCH, 16, 16]  (b, j, m)  cumulative v
    float* __restrict__ partial)       // [NG, BATCH, 256]
{
    const int tid = threadIdx.x;
    const int j = tid & 15;
    const int m = tid >> 4;
    const int g = blockIdx.x & (NG - 1);   // i-group; same-g blocks are 128 apart -> same XCD slot
    const int bg = blockIdx.x >> 7;        // 0..3 b-group
    const int i0 = g * NI;
    const int b0 = bg * NB;
    const int wave = tid >> 6;
    const int lane = tid & 63;

    __shared__ float w_lds[16 * 260];      // W[i] staged, row stride 260 (16B aligned, conflict-free)
    __shared__ float red[2][4][16];        // cross-wave logit partials, double buffered
    __shared__ float outx[2][17 * 16];     // output transpose bounce

    // preload Vcum[(b0+b), j, m] for my (j,m) across my 16 b's
    float vc[NB];
    if (!FIRST) {
#pragma unroll
        for (int b = 0; b < NB; ++b)
            vc[b] = vcum[(b0 + b) * 256 + j * 16 + m];
    }

    float acc[NB];
#pragma unroll
    for (int b = 0; b < NB; ++b) acc[b] = 0.0f;

    for (int ii = 0; ii < NI; ++ii) {
        const int i = i0 + ii;
        // ---- stage W[i] (4096 floats) into LDS, coalesced ----
        const float4* wg = (const float4*)(Wt + (size_t)i * 4096 + (size_t)tid * 16);
        float4 a0 = wg[0], a1 = wg[1], a2 = wg[2], a3 = wg[3];
        __syncthreads();   // WAR: previous iter's refill / red usage done
        {
            // thread t covers elements t*16..t*16+15: row = t>>4, col base = (t&15)*16
            float* dst = &w_lds[(tid >> 4) * 260 + (tid & 15) * 16];
            *(float4*)(dst + 0) = a0;
            *(float4*)(dst + 4) = a1;
            *(float4*)(dst + 8) = a2;
            *(float4*)(dst + 12) = a3;
        }
        __syncthreads();
        // ---- refill my W fragment: w[n] = W[i, j, n, m] ----
        float w[16];
#pragma unroll
        for (int n = 0; n < 16; ++n)
            w[n] = w_lds[j * 260 + n * 16 + m];

        // ---- loop over my 16 b's ----
#pragma unroll
        for (int b = 0; b < NB; ++b) {
            const float4* up = (const float4*)(inp + ((size_t)(b0 + b) * IC + i) * 16);
            float4 ua = up[0], ub = up[1], uc = up[2], ud = up[3];
            float p0 = w[0] * ua.x;  p0 = fmaf(w[1], ua.y, p0);
            p0 = fmaf(w[2], ua.z, p0);  p0 = fmaf(w[3], ua.w, p0);
            float p1 = w[4] * ub.x;  p1 = fmaf(w[5], ub.y, p1);
            p1 = fmaf(w[6], ub.z, p1);  p1 = fmaf(w[7], ub.w, p1);
            float p2 = w[8] * uc.x;  p2 = fmaf(w[9], uc.y, p2);
            p2 = fmaf(w[10], uc.z, p2); p2 = fmaf(w[11], uc.w, p2);
            float p3 = w[12] * ud.x; p3 = fmaf(w[13], ud.y, p3);
            p3 = fmaf(w[14], ud.z, p3); p3 = fmaf(w[15], ud.w, p3);
            const float hat = (p0 + p1) + (p2 + p3);

            if (FIRST) {
                acc[b] += hat;   // c = 1/16 uniform, folded into reducer scale
            } else {
                // logit[j] = sum_m vc*hat : reduce over m (lane bits 4,5 intra-wave, then LDS cross-wave)
                float t = vc[b] * hat;
                t += __shfl_xor(t, 16);
                t += __shfl_xor(t, 32);
                if (lane < 16) red[b & 1][wave][lane] = t;
                __syncthreads();
                const float logit = red[b & 1][0][j] + red[b & 1][1][j] +
                                    red[b & 1][2][j] + red[b & 1][3][j];
                // softmax over j (lane bits 0..3). |logit| <= ~16 -> exp safe without max-sub.
                const float e = __expf(logit);
                float s = e;
                s += __shfl_xor(s, 1);
                s += __shfl_xor(s, 2);
                s += __shfl_xor(s, 4);
                s += __shfl_xor(s, 8);
                const float c = e * __builtin_amdgcn_rcpf(s);
                acc[b] = fmaf(c, hat, acc[b]);
            }
        }
    }

    // ---- write partials [g][b][j*16+m], transposed via LDS for coalescing ----
#pragma unroll
    for (int b = 0; b < NB; ++b) {
        if (b < 2) __syncthreads();   // guard first writes vs last red/w_lds reads
        outx[b & 1][j * 17 + m] = acc[b];
        __syncthreads();
        partial[((size_t)g * BATCH + (b0 + b)) * 256 + tid] =
            outx[b & 1][(tid >> 4) * 17 + (tid & 15)];
    }
}

// One block per b. Reduce partials over NG groups, squash, update vcum / write out.
__global__ __launch_bounds__(256) void reduce_squash(
    const float* __restrict__ partial, float* __restrict__ vcum,
    float* __restrict__ out, int stage)
{
    const int b = blockIdx.x;
    const int tid = threadIdx.x;   // e = j*16 + m ; m = tid&15
    const float* p = partial + (size_t)b * 256 + tid;
    float s = 0.0f;
#pragma unroll 4
    for (int gi = 0; gi < NG; ++gi)
        s += p[(size_t)gi * BATCH * 256];
    if (stage == 0) s *= (1.0f / 16.0f);   // uniform c = 1/16 on iteration 0

    float n2 = s * s;
    n2 += __shfl_xor(n2, 1);
    n2 += __shfl_xor(n2, 2);
    n2 += __shfl_xor(n2, 4);
    n2 += __shfl_xor(n2, 8);
    const float scale = n2 / ((1.0f + n2) * sqrtf(n2 + 1e-8f));
    const float v = scale * s;

    const int o = b * 256 + tid;
    if (stage == 0)      vcum[o] = v;
    else if (stage == 1) vcum[o] += v;
    else                 out[o] = v;
}

extern "C" void kernel_launch(void* const* d_in, const int* in_sizes, int n_in,
                              void* d_out, int out_size, void* d_ws, size_t ws_size,
                              hipStream_t stream) {
    const float* inp = (const float*)d_in[0];   // [64, 2048, 16]
    const float* Wt  = (const float*)d_in[1];   // [2048, 16, 16, 16]
    float* out = (float*)d_out;                 // [64, 16, 16]
    float* partial = (float*)d_ws;              // NG*BATCH*256 floats = 8 MB
    float* vcum = partial + (size_t)NG * BATCH * 256;  // 64 KB

    const dim3 gp(NG * NBG), bp(256);

    // iter 0: c uniform -> s0 ; v0 = squash(s0/16); vcum = v0
    pass_kernel<true><<<gp, bp, 0, stream>>>(Wt, inp, nullptr, partial);
    reduce_squash<<<BATCH, 256, 0, stream>>>(partial, vcum, out, 0);
    // iter 1: logits from vcum=v0 -> s1 ; vcum += v1
    pass_kernel<false><<<gp, bp, 0, stream>>>(Wt, inp, vcum, partial);
    reduce_squash<<<BATCH, 256, 0, stream>>>(partial, vcum, out, 1);
    // iter 2: logits from vcum=v0+v1 -> s2 ; out = squash(s2)
    pass_kernel<false><<<gp, bp, 0, stream>>>(Wt, inp, vcum, partial);
    reduce_squash<<<BATCH, 256, 0, stream>>>(partial, vcum, out, 2);
}